// Round 3
// baseline (899.505 us; speedup 1.0000x reference)
//
#include <hip/hip_runtime.h>

// R7: fully DS-free chain. Builds on R6 (transpose-free MFMA chaining via
// hidden-channel permutation pi; zero LDS staging; no barriers).
// New in R7:
//  (a) layer-3 output gather via v_permlane16_swap_b32 (full-rate VALU)
//      instead of 8 ds_bpermute: W3/b3 are duplicated into C rows 8-15
//      (ch = m16&7), so for acc reg r the 16-lane groups hold
//      [ch r, ch 4+r, ch r, ch 4+r]; one self-swap yields ch r and ch 4+r
//      on every lane. Duplicated rows are independent identical dot
//      products -> nn bit-identical to R6. Removes all DS ops + lgkmcnt.
//  (b) stage-invariant B-frag words (y/u parts) hoisted out of the RK
//      chain: built once per step per variant {p, pi, ps}; stages 2&3
//      share the pi variant. In-stage work is only the 4 x-derived words.
// sigma-folding retained: tanh(a)=1-2*sigma(2a), -2 and 2*log2(e) folded
// into weights/biases; activation = rcp(1+exp2(c)). All dot products
// bit-identical to R6 (same values, same k-slots, same rounding).

typedef _Float16 h2_t __attribute__((ext_vector_type(2)));
typedef _Float16 h8_t __attribute__((ext_vector_type(8)));
typedef __fp16  pk2_t __attribute__((ext_vector_type(2)));
typedef float f4_t __attribute__((ext_vector_type(4)));

union H8 { h8_t v; h2_t h[4]; int i[4]; int4 i4; };
union H2I { h2_t h; pk2_t p; int i; float _f; };

#define DEVI __device__ __forceinline__

DEVI float rcp_f(float x) { return __builtin_amdgcn_rcpf(x); }
#if __has_builtin(__builtin_amdgcn_exp2f)
DEVI float exp2_f(float x) { return __builtin_amdgcn_exp2f(x); }
#else
DEVI float exp2_f(float x) { return __expf(x * 0.69314718056f); }
#endif
DEVI int pkrtz_i(float a, float b) { H2I u; u.p = __builtin_amdgcn_cvt_pkrtz(a, b); return u.i; }
DEVI h2_t pkrtz(float a, float b)  { H2I u; u.p = __builtin_amdgcn_cvt_pkrtz(a, b); return u.h; }
DEVI int h2i(h2_t h) { H2I u; u.h = h; return u.i; }

DEVI f4_t mfma16(h8_t a, h8_t b, f4_t c) {
    return __builtin_amdgcn_mfma_f32_16x16x32_f16(a, b, c, 0, 0, 0);
}

// hidden-channel permutation: physical channel computed at A-tile ct, row rho
DEVI int chan_of(int ct, int rho) {
    int qr = rho >> 2, rr = rho & 3;
    return (ct < 2) ? (8 * qr + 4 * ct + rr)
                    : (32 + 8 * qr + 4 * (ct - 2) + rr);
}

// grey-box CSTR+flash RHS, scaled coords, per-lane (batch = lane&15)
DEVI void fg_eval(const float x[8], float F, float D, float kfg[8]) {
    float Hr  = fmaf(x[0], 0.3f, 0.7f);
    float CAr = fmaf(x[1], 0.2f, 0.5f);
    float CBr = fmaf(x[2], 0.2f, 0.5f);
    float Tr  = fmaf(x[3], 5.0f, 310.0f);
    float Hb  = fmaf(x[4], 0.3f, 0.7f);
    float CAb = fmaf(x[5], 0.2f, 0.5f);
    float CBb = fmaf(x[6], 0.2f, 0.5f);
    float Tb  = fmaf(x[7], 5.0f, 310.0f);

    float aA = 3.5f * CAb, aB = 1.1f * CBb;
    float rden = rcp_f(aA + aB);
    float CAd = aA * rden, CBd = aB * rden;
    float Fr = __builtin_amdgcn_sqrtf(Hr);
    float Fb = __builtin_amdgcn_sqrtf(Hb);
    float rTr = rcp_f(Tr);
    float k1v = 20000.0f * __expf(-3000.0f * rTr);
    float r1 = k1v * CAr;
    float rHr = rcp_f(Hr), rHb = rcp_f(Hb);

    float dHr  = F + D - Fr;
    float dCAr = (F * (1.0f - CAr) + D * (CAd - CAr)) * rHr - r1;
    float dCBr = (D * (CBd - CBr) - F * CBr) * rHr + r1;
    float dTr  = (F * (320.0f - Tr) + D * (310.0f - Tr)) * rHr
               - (40.0f / 3.0f) * rHr + (2.0f / 3.0f) * r1;
    float dHb  = Fr - Fb - D;
    float dCAb = (Fr * (CAr - CAb) + D * (CAb - CAd)) * rHb;
    float dCBb = (Fr * (CBr - CBb) + D * (CBb - CBd)) * rHb;
    float dTb  = Fr * (Tr - Tb) * rHb + (40.0f / 3.0f) * rHb;

    kfg[0] = dHr  * (10.0f / 3.0f);
    kfg[1] = dCAr * 5.0f;
    kfg[2] = dCBr * 5.0f;
    kfg[3] = dTr  * 0.2f;
    kfg[4] = dHb  * (10.0f / 3.0f);
    kfg[5] = dCAb * 5.0f;
    kfg[6] = dCBb * 5.0f;
    kfg[7] = dTb  * 0.2f;
}

struct Weights {
    h8_t a1[4][2], a2[4][2], a3[2];
    f4_t b1f[4], b2f[4], b3f;
};

DEVI int sigpair(float a, float b) {
    float s0 = rcp_f(1.0f + exp2_f(a));
    float s1 = rcp_f(1.0f + exp2_f(b));
    return pkrtz_i(s0, s1);
}

// sigma transition, fully register-local (pi channel assignment)
DEVI void transition_local(const f4_t a[4], H8& g0, H8& g1) {
    g0.i[0] = sigpair(a[0][0], a[0][1]);
    g0.i[1] = sigpair(a[0][2], a[0][3]);
    g0.i[2] = sigpair(a[1][0], a[1][1]);
    g0.i[3] = sigpair(a[1][2], a[1][3]);
    g1.i[0] = sigpair(a[2][0], a[2][1]);
    g1.i[1] = sigpair(a[2][2], a[2][3]);
    g1.i[2] = sigpair(a[3][0], a[3][1]);
    g1.i[3] = sigpair(a[3][2], a[3][3]);
}

// layer-3 gather: a3 reg r holds [ch r, ch 4+r, ch r, ch 4+r] across the
// 16-lane groups (W3 rows duplicated). Self permlane16_swap -> first reg
// has the even-group value (ch r) on all lanes, second the odd (ch 4+r).
DEVI void gather_nn(const f4_t& a3, float nn[8]) {
#pragma unroll
    for (int r = 0; r < 4; ++r) {
        int e = __float_as_int(a3[r]);
        int o = e;
        asm("v_permlane16_swap_b32 %0, %1" : "+v"(e), "+v"(o));
        nn[r]     = __int_as_float(e);
        nn[4 + r] = __int_as_float(o);
    }
}

// one RK slope: k = fg(x,u) + fnn([x, zvariant, u]); y/u frag words are
// precomputed (f0y, f1), only the x words are merged in-stage (q0 lanes).
DEVI void eval_stage(const float x[8], const H8& f0y, const H8& f1,
                     float F, float D, const Weights& W, int q, float k[8]) {
    H8 f0;
#pragma unroll
    for (int i = 0; i < 4; ++i) {
        int pxi = pkrtz_i(x[2 * i], x[2 * i + 1]);
        f0.i[i] = (q == 0) ? pxi : f0y.i[i];
    }

    // ---- layer 1 (all 4 M-tiles, pi-permuted channels) ----
    f4_t a[4];
#pragma unroll
    for (int ct = 0; ct < 4; ++ct) {
        a[ct] = mfma16(W.a1[ct][0], f0.v, W.b1f[ct]);
        a[ct] = mfma16(W.a1[ct][1], f1.v, a[ct]);
    }
    H8 g0, g1;
    transition_local(a, g0, g1);

    // ---- layer 2 ----
#pragma unroll
    for (int ct = 0; ct < 4; ++ct) {
        a[ct] = mfma16(W.a2[ct][0], g0.v, W.b2f[ct]);
        a[ct] = mfma16(W.a2[ct][1], g1.v, a[ct]);
    }
    transition_local(a, g0, g1);

    // ---- layer 3 (full K; rows duplicated ch=row&7) ----
    f4_t a3 = mfma16(W.a3[0], g0.v, W.b3f);
    a3 = mfma16(W.a3[1], g1.v, a3);

    float nn[8];
    gather_nn(a3, nn);

    float kfg[8];
    fg_eval(x, F, D, kfg);
#pragma unroll
    for (int c = 0; c < 8; ++c) k[c] = kfg[c] + nn[c];
}

// build the stage-invariant frag words for one y-variant
DEVI void build_frags(const h2_t yv[16], const H8& f1c, int q,
                      H8& f0y, H8& f1) {
#pragma unroll
    for (int i = 0; i < 4; ++i) {
        int t = (q == 2) ? h2i(yv[4 + i]) : h2i(yv[8 + i]);
        f0y.i[i] = (q == 1) ? h2i(yv[i]) : t;
        f1.i[i]  = (q == 0) ? h2i(yv[12 + i]) : f1c.i[i];
    }
}

__global__ __launch_bounds__(64, 1)
void cstr_mfma1_kernel(const float* __restrict__ useq, const float* __restrict__ xGz0,
                       const float* __restrict__ W1, const float* __restrict__ b1,
                       const float* __restrict__ W2, const float* __restrict__ b2,
                       const float* __restrict__ W3, const float* __restrict__ b3,
                       float* __restrict__ out)
{
    const int lane = threadIdx.x & 63;
    const int m16 = lane & 15, q = lane >> 4;
    const int b0 = blockIdx.x * 16;

    const float S1 = 2.0f * 1.4426950408889634f;   // 2*log2(e)

    // ---- preload weights (sigma-folded, pi-permuted output columns) ----
    Weights W;
#pragma unroll
    for (int ct = 0; ct < 4; ++ct) {
        const int n = chan_of(ct, m16);            // A-frag row m16 -> channel
#pragma unroll
        for (int kh = 0; kh < 2; ++kh) {
            H8 w1f, w2f;
#pragma unroll
            for (int j = 0; j < 8; ++j) {
                int k = 32 * kh + 8 * q + j;
                float v1 = (k < 50) ? S1 * W1[k * 64 + n] : 0.0f;
                float v2 = -2.0f * S1 * W2[k * 64 + n];
                ((_Float16*)&w1f)[j] = (_Float16)v1;
                ((_Float16*)&w2f)[j] = (_Float16)v2;
            }
            W.a1[ct][kh] = w1f.v;
            W.a2[ct][kh] = w2f.v;
        }
        f4_t bb1, bb2;
#pragma unroll
        for (int r = 0; r < 4; ++r) {
            int ch = chan_of(ct, 4 * q + r);       // C slot (ct,q,r) -> channel
            bb1[r] = S1 * b1[ch];
            float cs = 0.0f;
            for (int j = 0; j < 64; ++j) cs += W2[j * 64 + ch];
            bb2[r] = S1 * (b2[ch] + cs);
        }
        W.b1f[ct] = bb1;
        W.b2f[ct] = bb2;
    }
    // layer 3: duplicate channels into rows 8-15 (ch = row&7) for the
    // permlane gather; duplicated rows are identical independent dots.
#pragma unroll
    for (int kh = 0; kh < 2; ++kh) {
        H8 w3f;
#pragma unroll
        for (int j = 0; j < 8; ++j) {
            int k = 32 * kh + 8 * q + j;
            ((_Float16*)&w3f)[j] = (_Float16)(-2.0f * W3[k * 8 + (m16 & 7)]);
        }
        W.a3[kh] = w3f.v;
    }
    {
        f4_t bb3;
#pragma unroll
        for (int r = 0; r < 4; ++r) {
            int c = (4 * q + r) & 7;
            float cs = 0.0f;
            for (int j = 0; j < 64; ++j) cs += W3[j * 8 + c];
            bb3[r] = b3[c] + cs;
        }
        W.b3f = bb3;
    }

    // ---- per-batch state (batch = lane&15; replicated across quads) ----
    const float* xz = xGz0 + (size_t)(b0 + m16) * 48;
    float xg[8];
#pragma unroll
    for (int c = 0; c < 8; ++c) xg[c] = xz[c];
    h2_t p[16];
#pragma unroll
    for (int i = 0; i < 16; ++i) p[i] = pkrtz(xz[8 + 2 * i], xz[9 + 2 * i]);
    h2_t up[4];
#pragma unroll
    for (int i = 0; i < 4; ++i) up[i] = pkrtz(xz[40 + 2 * i], xz[41 + 2 * i]);

    const float* ub = useq + (size_t)(b0 + m16) * 512;
    float* ob = out + (size_t)(b0 + m16) * 2048;

    float kc[8], ks[8], xv[8];

    float2 uu = *(const float2*)(ub);       // u for t=0

#pragma unroll 1
    for (int t = 0; t < 256; ++t) {
        // prefetch next step's u (wraps harmlessly at t=255)
        const float2 uun = *(const float2*)(ub + ((2 * t + 2) & 511));

        const float u0 = uu.x, u1 = uu.y;
        const float F = fmaf(u0, 0.1f, 1.0f);
        const float D = fmaf(u1, 0.05f, 0.5f);
        const int upair_i = pkrtz_i(u0, u1);

        // ycat pairs = [ypseq(16 pairs), xG(4 pairs)]
        h2_t pc[20];
#pragma unroll
        for (int i = 0; i < 16; ++i) pc[i] = p[i];
#pragma unroll
        for (int i = 0; i < 4; ++i) pc[16 + i] = pkrtz(xg[2 * i], xg[2 * i + 1]);
        h2_t pi[16], ps[16];
        const h2_t half2c = { (_Float16)0.5f, (_Float16)0.5f };
#pragma unroll
        for (int i = 0; i < 16; ++i) {
            pi[i] = (pc[i] + pc[i + 4]) * half2c;
            ps[i] = pc[i + 4];
        }

        // ---- stage-invariant frag words, built once per step ----
        H8 f1c;                                 // common u-part of f1
#pragma unroll
        for (int i = 0; i < 4; ++i) {
            int t0 = (i == 0) ? ((q == 2) ? upair_i : 0) : 0;
            f1c.i[i] = (q == 1) ? h2i(up[i]) : t0;
        }
        H8 f0yA, f1A, f0yB, f1B, f0yC, f1C;
        build_frags(p,  f1c, q, f0yA, f1A);     // stage 1
        build_frags(pi, f1c, q, f0yB, f1B);     // stages 2 & 3
        build_frags(ps, f1c, q, f0yC, f1C);     // stage 4

        // ---- RK4 (all register-local; no LDS, no DS, no barriers) ----
        eval_stage(xg, f0yA, f1A, F, D, W, q, kc);
#pragma unroll
        for (int c = 0; c < 8; ++c) { ks[c] = kc[c]; xv[c] = fmaf(0.005f, kc[c], xg[c]); }
        eval_stage(xv, f0yB, f1B, F, D, W, q, kc);
#pragma unroll
        for (int c = 0; c < 8; ++c) { ks[c] = fmaf(2.0f, kc[c], ks[c]); xv[c] = fmaf(0.005f, kc[c], xg[c]); }
        eval_stage(xv, f0yB, f1B, F, D, W, q, kc);
#pragma unroll
        for (int c = 0; c < 8; ++c) { ks[c] = fmaf(2.0f, kc[c], ks[c]); xv[c] = fmaf(0.01f, kc[c], xg[c]); }
        eval_stage(xv, f0yC, f1C, F, D, W, q, kc);

        // ---- store y_t = xG (pre-update) ----
        {
            float s0 = (q == 0) ? xg[0] : (q == 1) ? xg[2] : (q == 2) ? xg[4] : xg[6];
            float s1 = (q == 0) ? xg[1] : (q == 1) ? xg[3] : (q == 2) ? xg[5] : xg[7];
            float2 st = { s0, s1 };
            *(float2*)(ob + t * 8 + 2 * q) = st;
        }

        // ---- state update ----
#pragma unroll
        for (int c = 0; c < 8; ++c) {
            ks[c] += kc[c];
            xg[c] = fmaf(0.0016666667f, ks[c], xg[c]);   // DELTA/6
        }
#pragma unroll
        for (int i = 0; i < 16; ++i) p[i] = ps[i];
        up[0] = up[1]; up[1] = up[2]; up[2] = up[3];
        { H2I u; u.i = upair_i; up[3] = u.h; }

        uu = uun;
    }
}

extern "C" void kernel_launch(void* const* d_in, const int* in_sizes, int n_in,
                              void* d_out, int out_size, void* d_ws, size_t ws_size,
                              hipStream_t stream) {
    const float* useq = (const float*)d_in[0];
    const float* xGz0 = (const float*)d_in[1];
    const float* W1   = (const float*)d_in[2];
    const float* b1   = (const float*)d_in[3];
    const float* W2   = (const float*)d_in[4];
    const float* b2   = (const float*)d_in[5];
    const float* W3   = (const float*)d_in[6];
    const float* b3   = (const float*)d_in[7];
    float* out = (float*)d_out;

    // 8192 batch / 16 per group = 512 blocks of 1 wave (all channels)
    cstr_mfma1_kernel<<<dim3(512), dim3(64), 0, stream>>>(
        useq, xGz0, W1, b1, W2, b2, W3, b3, out);
}

// Round 4
// 898.985 us; speedup vs baseline: 1.0006x; 1.0006x over previous
//
#include <hip/hip_runtime.h>

// R8: R7's design (permlane gather + hoisted frags) with the alloca->LDS
// regression fixed. R7's step-scope H8 union aggregates passed by reference
// defeated SROA; AMDGPUPromoteAlloca put 4 KB in LDS + scratch spills
// (counters: LDS_Block_Size 4096, 2.15e7 bank conflicts, +3.7MB writes).
// R8 keeps every cross-stage value as a first-class ext-vector SSA value
// (i4_t by value, __builtin_bit_cast to h8_t at use), and the MFMA
// accumulators as named scalars. Zero LDS, zero DS ops, no barriers.
//  - layer-3 gather: W3/b3 duplicated into C rows 8-15 (ch=m16&7); one
//    v_permlane16_swap_b32 per acc reg yields ch r + ch 4+r on all lanes.
//  - stage-invariant B-frag words built once per step per y-variant
//    {p, pi, ps}; stages 2&3 share pi. Only x-words merge in-stage.
//  - pi channel permutation (R6) keeps the inter-layer transition fully
//    register-local: lane's 16 C-outputs == its 16 next-layer B-inputs.
// sigma-folding: tanh(a)=1-2*sigma(2a), -2 and 2*log2(e) folded into
// weights/biases; activation = rcp(1+exp2(c)). Bit-identical to R6/R7.

typedef _Float16 h2_t __attribute__((ext_vector_type(2)));
typedef _Float16 h8_t __attribute__((ext_vector_type(8)));
typedef __fp16  pk2_t __attribute__((ext_vector_type(2)));
typedef float f4_t __attribute__((ext_vector_type(4)));
typedef int   i4_t __attribute__((ext_vector_type(4)));

union H2I { h2_t h; pk2_t p; int i; float _f; };

#define DEVI __device__ __forceinline__

DEVI float rcp_f(float x) { return __builtin_amdgcn_rcpf(x); }
#if __has_builtin(__builtin_amdgcn_exp2f)
DEVI float exp2_f(float x) { return __builtin_amdgcn_exp2f(x); }
#else
DEVI float exp2_f(float x) { return __expf(x * 0.69314718056f); }
#endif
DEVI int pkrtz_i(float a, float b) { H2I u; u.p = __builtin_amdgcn_cvt_pkrtz(a, b); return u.i; }
DEVI h2_t pkrtz(float a, float b)  { H2I u; u.p = __builtin_amdgcn_cvt_pkrtz(a, b); return u.h; }
DEVI int h2i(h2_t h) { H2I u; u.h = h; return u.i; }

DEVI f4_t mfma16(h8_t a, h8_t b, f4_t c) {
    return __builtin_amdgcn_mfma_f32_16x16x32_f16(a, b, c, 0, 0, 0);
}

// hidden-channel permutation: physical channel computed at A-tile ct, row rho
DEVI int chan_of(int ct, int rho) {
    int qr = rho >> 2, rr = rho & 3;
    return (ct < 2) ? (8 * qr + 4 * ct + rr)
                    : (32 + 8 * qr + 4 * (ct - 2) + rr);
}

// grey-box CSTR+flash RHS, scaled coords, per-lane (batch = lane&15)
DEVI void fg_eval(const float x[8], float F, float D, float kfg[8]) {
    float Hr  = fmaf(x[0], 0.3f, 0.7f);
    float CAr = fmaf(x[1], 0.2f, 0.5f);
    float CBr = fmaf(x[2], 0.2f, 0.5f);
    float Tr  = fmaf(x[3], 5.0f, 310.0f);
    float Hb  = fmaf(x[4], 0.3f, 0.7f);
    float CAb = fmaf(x[5], 0.2f, 0.5f);
    float CBb = fmaf(x[6], 0.2f, 0.5f);
    float Tb  = fmaf(x[7], 5.0f, 310.0f);

    float aA = 3.5f * CAb, aB = 1.1f * CBb;
    float rden = rcp_f(aA + aB);
    float CAd = aA * rden, CBd = aB * rden;
    float Fr = __builtin_amdgcn_sqrtf(Hr);
    float Fb = __builtin_amdgcn_sqrtf(Hb);
    float rTr = rcp_f(Tr);
    float k1v = 20000.0f * __expf(-3000.0f * rTr);
    float r1 = k1v * CAr;
    float rHr = rcp_f(Hr), rHb = rcp_f(Hb);

    float dHr  = F + D - Fr;
    float dCAr = (F * (1.0f - CAr) + D * (CAd - CAr)) * rHr - r1;
    float dCBr = (D * (CBd - CBr) - F * CBr) * rHr + r1;
    float dTr  = (F * (320.0f - Tr) + D * (310.0f - Tr)) * rHr
               - (40.0f / 3.0f) * rHr + (2.0f / 3.0f) * r1;
    float dHb  = Fr - Fb - D;
    float dCAb = (Fr * (CAr - CAb) + D * (CAb - CAd)) * rHb;
    float dCBb = (Fr * (CBr - CBb) + D * (CBb - CBd)) * rHb;
    float dTb  = Fr * (Tr - Tb) * rHb + (40.0f / 3.0f) * rHb;

    kfg[0] = dHr  * (10.0f / 3.0f);
    kfg[1] = dCAr * 5.0f;
    kfg[2] = dCBr * 5.0f;
    kfg[3] = dTr  * 0.2f;
    kfg[4] = dHb  * (10.0f / 3.0f);
    kfg[5] = dCAb * 5.0f;
    kfg[6] = dCBb * 5.0f;
    kfg[7] = dTb  * 0.2f;
}

struct Weights {
    h8_t a1[4][2], a2[4][2], a3[2];
    f4_t b1f[4], b2f[4], b3f;
};

DEVI int sigpair(float a, float b) {
    float s0 = rcp_f(1.0f + exp2_f(a));
    float s1 = rcp_f(1.0f + exp2_f(b));
    return pkrtz_i(s0, s1);
}

// sigma transition for two C-tiles -> one B-frag (register-local, SSA)
DEVI h8_t sig4(f4_t a0, f4_t a1) {
    i4_t g;
    g[0] = sigpair(a0[0], a0[1]);
    g[1] = sigpair(a0[2], a0[3]);
    g[2] = sigpair(a1[0], a1[1]);
    g[3] = sigpair(a1[2], a1[3]);
    return __builtin_bit_cast(h8_t, g);
}

// layer-3 gather: a3 reg r holds [ch r, ch 4+r, ch r, ch 4+r] across the
// 16-lane groups (W3 rows duplicated). Self permlane16_swap -> first reg
// has the even-group value (ch r) on all lanes, second the odd (ch 4+r).
DEVI void gather_nn(f4_t a3, float nn[8]) {
#pragma unroll
    for (int r = 0; r < 4; ++r) {
        int e = __float_as_int(a3[r]);
        int o = e;
        asm("v_permlane16_swap_b32 %0, %1" : "+v"(e), "+v"(o));
        nn[r]     = __int_as_float(e);
        nn[4 + r] = __int_as_float(o);
    }
}

// one RK slope: k = fg(x,u) + fnn([x, zvariant, u]); y/u frag words are
// precomputed SSA values (f0y, f1w); only x-words merge here (q0 lanes).
DEVI void eval_stage(const float x[8], i4_t f0y, i4_t f1w,
                     float F, float D, const Weights& W, int q, float k[8]) {
    i4_t f0w;
#pragma unroll
    for (int i = 0; i < 4; ++i) {
        int pxi = pkrtz_i(x[2 * i], x[2 * i + 1]);
        f0w[i] = (q == 0) ? pxi : f0y[i];
    }
    h8_t f0 = __builtin_bit_cast(h8_t, f0w);
    h8_t f1 = __builtin_bit_cast(h8_t, f1w);

    // ---- layer 1 (4 M-tiles, pi-permuted channels) ----
    f4_t a0 = mfma16(W.a1[0][0], f0, W.b1f[0]); a0 = mfma16(W.a1[0][1], f1, a0);
    f4_t a1 = mfma16(W.a1[1][0], f0, W.b1f[1]); a1 = mfma16(W.a1[1][1], f1, a1);
    f4_t a2 = mfma16(W.a1[2][0], f0, W.b1f[2]); a2 = mfma16(W.a1[2][1], f1, a2);
    f4_t a3 = mfma16(W.a1[3][0], f0, W.b1f[3]); a3 = mfma16(W.a1[3][1], f1, a3);
    h8_t g0 = sig4(a0, a1);
    h8_t g1 = sig4(a2, a3);

    // ---- layer 2 ----
    a0 = mfma16(W.a2[0][0], g0, W.b2f[0]); a0 = mfma16(W.a2[0][1], g1, a0);
    a1 = mfma16(W.a2[1][0], g0, W.b2f[1]); a1 = mfma16(W.a2[1][1], g1, a1);
    a2 = mfma16(W.a2[2][0], g0, W.b2f[2]); a2 = mfma16(W.a2[2][1], g1, a2);
    a3 = mfma16(W.a2[3][0], g0, W.b2f[3]); a3 = mfma16(W.a2[3][1], g1, a3);
    g0 = sig4(a0, a1);
    g1 = sig4(a2, a3);

    // ---- layer 3 (full K; rows duplicated ch=row&7) ----
    f4_t acc3 = mfma16(W.a3[0], g0, W.b3f);
    acc3 = mfma16(W.a3[1], g1, acc3);

    float nn[8];
    gather_nn(acc3, nn);

    float kfg[8];
    fg_eval(x, F, D, kfg);
#pragma unroll
    for (int c = 0; c < 8; ++c) k[c] = kfg[c] + nn[c];
}

// stage-invariant f0 y-part for one y-variant (SSA return)
DEVI i4_t build_f0y(const h2_t yv[16], int q) {
    i4_t r;
#pragma unroll
    for (int i = 0; i < 4; ++i) {
        int t = (q == 2) ? h2i(yv[4 + i]) : h2i(yv[8 + i]);
        r[i] = (q == 1) ? h2i(yv[i]) : t;
    }
    return r;
}
// stage-invariant f1 for one y-variant (SSA return)
DEVI i4_t build_f1(const h2_t yv[16], i4_t f1c, int q) {
    i4_t r;
#pragma unroll
    for (int i = 0; i < 4; ++i)
        r[i] = (q == 0) ? h2i(yv[12 + i]) : f1c[i];
    return r;
}

__global__ __launch_bounds__(64, 1)
void cstr_mfma1_kernel(const float* __restrict__ useq, const float* __restrict__ xGz0,
                       const float* __restrict__ W1, const float* __restrict__ b1,
                       const float* __restrict__ W2, const float* __restrict__ b2,
                       const float* __restrict__ W3, const float* __restrict__ b3,
                       float* __restrict__ out)
{
    const int lane = threadIdx.x & 63;
    const int m16 = lane & 15, q = lane >> 4;
    const int b0 = blockIdx.x * 16;

    const float S1 = 2.0f * 1.4426950408889634f;   // 2*log2(e)

    // ---- preload weights (sigma-folded, pi-permuted output columns) ----
    Weights W;
#pragma unroll
    for (int ct = 0; ct < 4; ++ct) {
        const int n = chan_of(ct, m16);            // A-frag row m16 -> channel
#pragma unroll
        for (int kh = 0; kh < 2; ++kh) {
            i4_t w1f, w2f;
#pragma unroll
            for (int jj = 0; jj < 4; ++jj) {
                int k0 = 32 * kh + 8 * q + 2 * jj;
                int k1 = k0 + 1;
                float v1a = (k0 < 50) ? S1 * W1[k0 * 64 + n] : 0.0f;
                float v1b = (k1 < 50) ? S1 * W1[k1 * 64 + n] : 0.0f;
                float v2a = -2.0f * S1 * W2[k0 * 64 + n];
                float v2b = -2.0f * S1 * W2[k1 * 64 + n];
                w1f[jj] = pkrtz_i(v1a, v1b);
                w2f[jj] = pkrtz_i(v2a, v2b);
            }
            W.a1[ct][kh] = __builtin_bit_cast(h8_t, w1f);
            W.a2[ct][kh] = __builtin_bit_cast(h8_t, w2f);
        }
        f4_t bb1, bb2;
#pragma unroll
        for (int r = 0; r < 4; ++r) {
            int ch = chan_of(ct, 4 * q + r);       // C slot (ct,q,r) -> channel
            bb1[r] = S1 * b1[ch];
            float cs = 0.0f;
            for (int j = 0; j < 64; ++j) cs += W2[j * 64 + ch];
            bb2[r] = S1 * (b2[ch] + cs);
        }
        W.b1f[ct] = bb1;
        W.b2f[ct] = bb2;
    }
    // layer 3: duplicate channels into rows 8-15 (ch = row&7) for the
    // permlane gather; duplicated rows are identical independent dots.
#pragma unroll
    for (int kh = 0; kh < 2; ++kh) {
        i4_t w3f;
#pragma unroll
        for (int jj = 0; jj < 4; ++jj) {
            int k0 = 32 * kh + 8 * q + 2 * jj;
            float va = -2.0f * W3[k0 * 8 + (m16 & 7)];
            float vb = -2.0f * W3[(k0 + 1) * 8 + (m16 & 7)];
            w3f[jj] = pkrtz_i(va, vb);
        }
        W.a3[kh] = __builtin_bit_cast(h8_t, w3f);
    }
    {
        f4_t bb3;
#pragma unroll
        for (int r = 0; r < 4; ++r) {
            int c = (4 * q + r) & 7;
            float cs = 0.0f;
            for (int j = 0; j < 64; ++j) cs += W3[j * 8 + c];
            bb3[r] = b3[c] + cs;
        }
        W.b3f = bb3;
    }

    // ---- per-batch state (batch = lane&15; replicated across quads) ----
    const float* xz = xGz0 + (size_t)(b0 + m16) * 48;
    float xg[8];
#pragma unroll
    for (int c = 0; c < 8; ++c) xg[c] = xz[c];
    h2_t p[16];
#pragma unroll
    for (int i = 0; i < 16; ++i) p[i] = pkrtz(xz[8 + 2 * i], xz[9 + 2 * i]);
    h2_t up[4];
#pragma unroll
    for (int i = 0; i < 4; ++i) up[i] = pkrtz(xz[40 + 2 * i], xz[41 + 2 * i]);

    const float* ub = useq + (size_t)(b0 + m16) * 512;
    float* ob = out + (size_t)(b0 + m16) * 2048;

    float kc[8], ks[8], xv[8];

    float2 uu = *(const float2*)(ub);       // u for t=0

#pragma unroll 1
    for (int t = 0; t < 256; ++t) {
        // prefetch next step's u (wraps harmlessly at t=255)
        const float2 uun = *(const float2*)(ub + ((2 * t + 2) & 511));

        const float u0 = uu.x, u1 = uu.y;
        const float F = fmaf(u0, 0.1f, 1.0f);
        const float D = fmaf(u1, 0.05f, 0.5f);
        const int upair_i = pkrtz_i(u0, u1);

        // ycat pairs = [ypseq(16 pairs), xG(4 pairs)]
        h2_t pc[20];
#pragma unroll
        for (int i = 0; i < 16; ++i) pc[i] = p[i];
#pragma unroll
        for (int i = 0; i < 4; ++i) pc[16 + i] = pkrtz(xg[2 * i], xg[2 * i + 1]);
        h2_t pi[16], ps[16];
        const h2_t half2c = { (_Float16)0.5f, (_Float16)0.5f };
#pragma unroll
        for (int i = 0; i < 16; ++i) {
            pi[i] = (pc[i] + pc[i + 4]) * half2c;
            ps[i] = pc[i + 4];
        }

        // ---- stage-invariant frag words (SSA i4_t values) ----
        i4_t f1c;
#pragma unroll
        for (int i = 0; i < 4; ++i) {
            int t0 = (i == 0) ? ((q == 2) ? upair_i : 0) : 0;
            f1c[i] = (q == 1) ? h2i(up[i]) : t0;
        }
        i4_t f0yA = build_f0y(p,  q), f1A = build_f1(p,  f1c, q);
        i4_t f0yB = build_f0y(pi, q), f1B = build_f1(pi, f1c, q);
        i4_t f0yC = build_f0y(ps, q), f1C = build_f1(ps, f1c, q);

        // ---- RK4 (all register-local; no LDS, no DS, no barriers) ----
        eval_stage(xg, f0yA, f1A, F, D, W, q, kc);
#pragma unroll
        for (int c = 0; c < 8; ++c) { ks[c] = kc[c]; xv[c] = fmaf(0.005f, kc[c], xg[c]); }
        eval_stage(xv, f0yB, f1B, F, D, W, q, kc);
#pragma unroll
        for (int c = 0; c < 8; ++c) { ks[c] = fmaf(2.0f, kc[c], ks[c]); xv[c] = fmaf(0.005f, kc[c], xg[c]); }
        eval_stage(xv, f0yB, f1B, F, D, W, q, kc);
#pragma unroll
        for (int c = 0; c < 8; ++c) { ks[c] = fmaf(2.0f, kc[c], ks[c]); xv[c] = fmaf(0.01f, kc[c], xg[c]); }
        eval_stage(xv, f0yC, f1C, F, D, W, q, kc);

        // ---- store y_t = xG (pre-update) ----
        {
            float s0 = (q == 0) ? xg[0] : (q == 1) ? xg[2] : (q == 2) ? xg[4] : xg[6];
            float s1 = (q == 0) ? xg[1] : (q == 1) ? xg[3] : (q == 2) ? xg[5] : xg[7];
            float2 st = { s0, s1 };
            *(float2*)(ob + t * 8 + 2 * q) = st;
        }

        // ---- state update ----
#pragma unroll
        for (int c = 0; c < 8; ++c) {
            ks[c] += kc[c];
            xg[c] = fmaf(0.0016666667f, ks[c], xg[c]);   // DELTA/6
        }
#pragma unroll
        for (int i = 0; i < 16; ++i) p[i] = ps[i];
        up[0] = up[1]; up[1] = up[2]; up[2] = up[3];
        { H2I u; u.i = upair_i; up[3] = u.h; }

        uu = uun;
    }
}

extern "C" void kernel_launch(void* const* d_in, const int* in_sizes, int n_in,
                              void* d_out, int out_size, void* d_ws, size_t ws_size,
                              hipStream_t stream) {
    const float* useq = (const float*)d_in[0];
    const float* xGz0 = (const float*)d_in[1];
    const float* W1   = (const float*)d_in[2];
    const float* b1   = (const float*)d_in[3];
    const float* W2   = (const float*)d_in[4];
    const float* b2   = (const float*)d_in[5];
    const float* W3   = (const float*)d_in[6];
    const float* b3   = (const float*)d_in[7];
    float* out = (float*)d_out;

    // 8192 batch / 16 per group = 512 blocks of 1 wave (all channels)
    cstr_mfma1_kernel<<<dim3(512), dim3(64), 0, stream>>>(
        useq, xGz0, W1, b1, W2, b2, W3, b3, out);
}

// Round 5
// 839.559 us; speedup vs baseline: 1.0714x; 1.0708x over previous
//
#include <hip/hip_runtime.h>

// R9: alloca-proof rewrite. R7/R8 kept showing LDS_Block_Size=4096 +
// 2.15e7 bank conflicts with zero __shared__ in source: AMDGPUPromoteAlloca
// was promoting a step-scope aggregate (h2 ring / nn out-param) to LDS,
// putting a 16-bank-stride LDS round-trip on the serial RK chain. R9
// eliminates the alloca CATEGORY: every loop-carried or cross-stage value
// is a first-class ext-vector SSA value (f8_t/i4_t) passed/returned BY
// VALUE. insert/extractelement never allocas -> nothing to promote.
//  - y-ring p[16] -> i4_t P0..P3 (packed h2 pairs); shift = reg renaming.
//  - variants: A=p (P0..P3), C=shifted (P1,P2,P3,XC), B=avg pairs.
//  - layer-3 gather: W3/b3 duplicated into C rows 8-15; one
//    v_permlane16_swap_b32 per acc reg (VALU, no DS ops).
//  - pi channel permutation (R6) keeps inter-layer transition in regs.
//  - stage-invariant frag words built once per step per variant.
// sigma-folding: tanh(a)=1-2*sigma(2a), -2 and 2*log2(e) folded into
// weights/biases; activation = rcp(1+exp2(c)). Numerics bit-identical
// to R6/R7/R8 (same ops, same order, same rounding points).

typedef _Float16 h2_t __attribute__((ext_vector_type(2)));
typedef _Float16 h8_t __attribute__((ext_vector_type(8)));
typedef __fp16  pk2_t __attribute__((ext_vector_type(2)));
typedef float f4_t __attribute__((ext_vector_type(4)));
typedef float f8_t __attribute__((ext_vector_type(8)));
typedef int   i4_t __attribute__((ext_vector_type(4)));

union H2I { h2_t h; pk2_t p; int i; float _f; };

#define DEVI __device__ __forceinline__

DEVI float rcp_f(float x) { return __builtin_amdgcn_rcpf(x); }
#if __has_builtin(__builtin_amdgcn_exp2f)
DEVI float exp2_f(float x) { return __builtin_amdgcn_exp2f(x); }
#else
DEVI float exp2_f(float x) { return __expf(x * 0.69314718056f); }
#endif
DEVI int pkrtz_i(float a, float b) { H2I u; u.p = __builtin_amdgcn_cvt_pkrtz(a, b); return u.i; }
DEVI int h2i(h2_t h) { H2I u; u.h = h; return u.i; }
DEVI h2_t i2h(int i) { H2I u; u.i = i; return u.h; }

DEVI f4_t mfma16(h8_t a, h8_t b, f4_t c) {
    return __builtin_amdgcn_mfma_f32_16x16x32_f16(a, b, c, 0, 0, 0);
}

// hidden-channel permutation: physical channel computed at A-tile ct, row rho
DEVI int chan_of(int ct, int rho) {
    int qr = rho >> 2, rr = rho & 3;
    return (ct < 2) ? (8 * qr + 4 * ct + rr)
                    : (32 + 8 * qr + 4 * (ct - 2) + rr);
}

// grey-box CSTR+flash RHS, scaled coords, per-lane (batch = lane&15)
DEVI f8_t fg_eval(f8_t x, float F, float D) {
    float Hr  = fmaf(x[0], 0.3f, 0.7f);
    float CAr = fmaf(x[1], 0.2f, 0.5f);
    float CBr = fmaf(x[2], 0.2f, 0.5f);
    float Tr  = fmaf(x[3], 5.0f, 310.0f);
    float Hb  = fmaf(x[4], 0.3f, 0.7f);
    float CAb = fmaf(x[5], 0.2f, 0.5f);
    float CBb = fmaf(x[6], 0.2f, 0.5f);
    float Tb  = fmaf(x[7], 5.0f, 310.0f);

    float aA = 3.5f * CAb, aB = 1.1f * CBb;
    float rden = rcp_f(aA + aB);
    float CAd = aA * rden, CBd = aB * rden;
    float Fr = __builtin_amdgcn_sqrtf(Hr);
    float Fb = __builtin_amdgcn_sqrtf(Hb);
    float rTr = rcp_f(Tr);
    float k1v = 20000.0f * __expf(-3000.0f * rTr);
    float r1 = k1v * CAr;
    float rHr = rcp_f(Hr), rHb = rcp_f(Hb);

    float dHr  = F + D - Fr;
    float dCAr = (F * (1.0f - CAr) + D * (CAd - CAr)) * rHr - r1;
    float dCBr = (D * (CBd - CBr) - F * CBr) * rHr + r1;
    float dTr  = (F * (320.0f - Tr) + D * (310.0f - Tr)) * rHr
               - (40.0f / 3.0f) * rHr + (2.0f / 3.0f) * r1;
    float dHb  = Fr - Fb - D;
    float dCAb = (Fr * (CAr - CAb) + D * (CAb - CAd)) * rHb;
    float dCBb = (Fr * (CBr - CBb) + D * (CBb - CBd)) * rHb;
    float dTb  = Fr * (Tr - Tb) * rHb + (40.0f / 3.0f) * rHb;

    f8_t kfg;
    kfg[0] = dHr  * (10.0f / 3.0f);
    kfg[1] = dCAr * 5.0f;
    kfg[2] = dCBr * 5.0f;
    kfg[3] = dTr  * 0.2f;
    kfg[4] = dHb  * (10.0f / 3.0f);
    kfg[5] = dCAb * 5.0f;
    kfg[6] = dCBb * 5.0f;
    kfg[7] = dTb  * 0.2f;
    return kfg;
}

struct Weights {
    h8_t a1[4][2], a2[4][2], a3[2];
    f4_t b1f[4], b2f[4], b3f;
};

DEVI int sigpair(float a, float b) {
    float s0 = rcp_f(1.0f + exp2_f(a));
    float s1 = rcp_f(1.0f + exp2_f(b));
    return pkrtz_i(s0, s1);
}

// sigma transition for two C-tiles -> one B-frag (register-local, SSA)
DEVI h8_t sig4(f4_t a0, f4_t a1) {
    i4_t g;
    g[0] = sigpair(a0[0], a0[1]);
    g[1] = sigpair(a0[2], a0[3]);
    g[2] = sigpair(a1[0], a1[1]);
    g[3] = sigpair(a1[2], a1[3]);
    return __builtin_bit_cast(h8_t, g);
}

// packed-f16 midpoint of 4 pairs: (a+b)*0.5h, same rounding as before
DEVI i4_t avg4(i4_t A, i4_t B) {
    const h2_t half2c = { (_Float16)0.5f, (_Float16)0.5f };
    i4_t r;
#pragma unroll
    for (int i = 0; i < 4; ++i)
        r[i] = h2i((i2h(A[i]) + i2h(B[i])) * half2c);
    return r;
}

// f0 y-part select: quad q picks its 4 pair-words of the variant
DEVI i4_t sel_f0y(i4_t V0, i4_t V1, i4_t V2, int q) {
    i4_t r;
#pragma unroll
    for (int i = 0; i < 4; ++i) {
        int t = (q == 2) ? V1[i] : V2[i];
        r[i] = (q == 1) ? V0[i] : t;
    }
    return r;
}
// f1 select: q0 lanes get variant pairs 12..15, others the common u-part
DEVI i4_t sel_f1(i4_t V3, i4_t f1c, int q) {
    i4_t r;
#pragma unroll
    for (int i = 0; i < 4; ++i)
        r[i] = (q == 0) ? V3[i] : f1c[i];
    return r;
}

// one RK slope: k = fg(x,u) + fnn([x, zvariant, u]); y/u frag words are
// precomputed SSA values; only the x-words merge here (q0 lanes).
DEVI f8_t eval_stage(f8_t x, i4_t f0y, i4_t f1w,
                     float F, float D, const Weights& W, int q) {
    i4_t f0w;
#pragma unroll
    for (int i = 0; i < 4; ++i) {
        int pxi = pkrtz_i(x[2 * i], x[2 * i + 1]);
        f0w[i] = (q == 0) ? pxi : f0y[i];
    }
    h8_t f0 = __builtin_bit_cast(h8_t, f0w);
    h8_t f1 = __builtin_bit_cast(h8_t, f1w);

    // ---- layer 1 (4 M-tiles, pi-permuted channels) ----
    f4_t a0 = mfma16(W.a1[0][0], f0, W.b1f[0]); a0 = mfma16(W.a1[0][1], f1, a0);
    f4_t a1 = mfma16(W.a1[1][0], f0, W.b1f[1]); a1 = mfma16(W.a1[1][1], f1, a1);
    f4_t a2 = mfma16(W.a1[2][0], f0, W.b1f[2]); a2 = mfma16(W.a1[2][1], f1, a2);
    f4_t a3 = mfma16(W.a1[3][0], f0, W.b1f[3]); a3 = mfma16(W.a1[3][1], f1, a3);
    h8_t g0 = sig4(a0, a1);
    h8_t g1 = sig4(a2, a3);

    // ---- layer 2 ----
    a0 = mfma16(W.a2[0][0], g0, W.b2f[0]); a0 = mfma16(W.a2[0][1], g1, a0);
    a1 = mfma16(W.a2[1][0], g0, W.b2f[1]); a1 = mfma16(W.a2[1][1], g1, a1);
    a2 = mfma16(W.a2[2][0], g0, W.b2f[2]); a2 = mfma16(W.a2[2][1], g1, a2);
    a3 = mfma16(W.a2[3][0], g0, W.b2f[3]); a3 = mfma16(W.a2[3][1], g1, a3);
    g0 = sig4(a0, a1);
    g1 = sig4(a2, a3);

    // ---- layer 3 (full K; rows duplicated ch=row&7) ----
    f4_t acc3 = mfma16(W.a3[0], g0, W.b3f);
    acc3 = mfma16(W.a3[1], g1, acc3);

    // gather: acc3 reg r holds [ch r, ch 4+r, ch r, ch 4+r] across 16-lane
    // groups; self permlane16_swap -> ch r and ch 4+r on every lane.
    f8_t nn;
#pragma unroll
    for (int r = 0; r < 4; ++r) {
        int e = __float_as_int(acc3[r]);
        int o = e;
        asm("v_permlane16_swap_b32 %0, %1" : "+v"(e), "+v"(o));
        nn[r]     = __int_as_float(e);
        nn[4 + r] = __int_as_float(o);
    }

    f8_t kfg = fg_eval(x, F, D);
    f8_t k;
#pragma unroll
    for (int c = 0; c < 8; ++c) k[c] = kfg[c] + nn[c];
    return k;
}

__global__ __launch_bounds__(64, 1)
void cstr_mfma1_kernel(const float* __restrict__ useq, const float* __restrict__ xGz0,
                       const float* __restrict__ W1, const float* __restrict__ b1,
                       const float* __restrict__ W2, const float* __restrict__ b2,
                       const float* __restrict__ W3, const float* __restrict__ b3,
                       float* __restrict__ out)
{
    const int lane = threadIdx.x & 63;
    const int m16 = lane & 15, q = lane >> 4;
    const int b0 = blockIdx.x * 16;

    const float S1 = 2.0f * 1.4426950408889634f;   // 2*log2(e)

    // ---- preload weights (sigma-folded, pi-permuted output columns) ----
    Weights W;
#pragma unroll
    for (int ct = 0; ct < 4; ++ct) {
        const int n = chan_of(ct, m16);            // A-frag row m16 -> channel
#pragma unroll
        for (int kh = 0; kh < 2; ++kh) {
            i4_t w1f, w2f;
#pragma unroll
            for (int jj = 0; jj < 4; ++jj) {
                int k0 = 32 * kh + 8 * q + 2 * jj;
                int k1 = k0 + 1;
                float v1a = (k0 < 50) ? S1 * W1[k0 * 64 + n] : 0.0f;
                float v1b = (k1 < 50) ? S1 * W1[k1 * 64 + n] : 0.0f;
                float v2a = -2.0f * S1 * W2[k0 * 64 + n];
                float v2b = -2.0f * S1 * W2[k1 * 64 + n];
                w1f[jj] = pkrtz_i(v1a, v1b);
                w2f[jj] = pkrtz_i(v2a, v2b);
            }
            W.a1[ct][kh] = __builtin_bit_cast(h8_t, w1f);
            W.a2[ct][kh] = __builtin_bit_cast(h8_t, w2f);
        }
        f4_t bb1, bb2;
#pragma unroll
        for (int r = 0; r < 4; ++r) {
            int ch = chan_of(ct, 4 * q + r);       // C slot (ct,q,r) -> channel
            bb1[r] = S1 * b1[ch];
            float cs = 0.0f;
            for (int j = 0; j < 64; ++j) cs += W2[j * 64 + ch];
            bb2[r] = S1 * (b2[ch] + cs);
        }
        W.b1f[ct] = bb1;
        W.b2f[ct] = bb2;
    }
    // layer 3: duplicate channels into rows 8-15 (ch = row&7) for the
    // permlane gather; duplicated rows are identical independent dots.
#pragma unroll
    for (int kh = 0; kh < 2; ++kh) {
        i4_t w3f;
#pragma unroll
        for (int jj = 0; jj < 4; ++jj) {
            int k0 = 32 * kh + 8 * q + 2 * jj;
            float va = -2.0f * W3[k0 * 8 + (m16 & 7)];
            float vb = -2.0f * W3[(k0 + 1) * 8 + (m16 & 7)];
            w3f[jj] = pkrtz_i(va, vb);
        }
        W.a3[kh] = __builtin_bit_cast(h8_t, w3f);
    }
    {
        f4_t bb3;
#pragma unroll
        for (int r = 0; r < 4; ++r) {
            int c = (4 * q + r) & 7;
            float cs = 0.0f;
            for (int j = 0; j < 64; ++j) cs += W3[j * 8 + c];
            bb3[r] = b3[c] + cs;
        }
        W.b3f = bb3;
    }

    // ---- per-batch state (batch = lane&15; replicated across quads) ----
    const float* xz = xGz0 + (size_t)(b0 + m16) * 48;
    f8_t xg;
#pragma unroll
    for (int c = 0; c < 8; ++c) xg[c] = xz[c];
    // y-ring as packed h2 pair-words: P0=pairs0-3, P1=4-7, P2=8-11, P3=12-15
    i4_t P0, P1, P2, P3, U;
#pragma unroll
    for (int i = 0; i < 4; ++i) {
        P0[i] = pkrtz_i(xz[ 8 + 2 * i], xz[ 9 + 2 * i]);
        P1[i] = pkrtz_i(xz[16 + 2 * i], xz[17 + 2 * i]);
        P2[i] = pkrtz_i(xz[24 + 2 * i], xz[25 + 2 * i]);
        P3[i] = pkrtz_i(xz[32 + 2 * i], xz[33 + 2 * i]);
        U[i]  = pkrtz_i(xz[40 + 2 * i], xz[41 + 2 * i]);
    }

    const float* ub = useq + (size_t)(b0 + m16) * 512;
    float* ob = out + (size_t)(b0 + m16) * 2048;

    float2 uu = *(const float2*)(ub);       // u for t=0

#pragma unroll 1
    for (int t = 0; t < 256; ++t) {
        // prefetch next step's u (wraps harmlessly at t=255)
        const float2 uun = *(const float2*)(ub + ((2 * t + 2) & 511));

        const float u0 = uu.x, u1 = uu.y;
        const float F = fmaf(u0, 0.1f, 1.0f);
        const float D = fmaf(u1, 0.05f, 0.5f);
        const int upair_i = pkrtz_i(u0, u1);

        // xG pairs (pc[16..19])
        i4_t XC;
#pragma unroll
        for (int i = 0; i < 4; ++i) XC[i] = pkrtz_i(xg[2 * i], xg[2 * i + 1]);

        // variant B (midpoint) pair-words
        i4_t B0 = avg4(P0, P1), B1 = avg4(P1, P2),
             B2 = avg4(P2, P3), B3 = avg4(P3, XC);

        // common u-part of f1
        i4_t f1c;
#pragma unroll
        for (int i = 0; i < 4; ++i) {
            int t0 = (i == 0) ? ((q == 2) ? upair_i : 0) : 0;
            f1c[i] = (q == 1) ? U[i] : t0;
        }

        // stage-invariant frag words (all SSA)
        i4_t f0yA = sel_f0y(P0, P1, P2, q), f1A = sel_f1(P3, f1c, q);
        i4_t f0yB = sel_f0y(B0, B1, B2, q), f1B = sel_f1(B3, f1c, q);
        i4_t f0yC = sel_f0y(P1, P2, P3, q), f1C = sel_f1(XC, f1c, q);

        // ---- RK4 (all register-local; no LDS, no DS, no barriers) ----
        f8_t kc, ks, xv;
        kc = eval_stage(xg, f0yA, f1A, F, D, W, q);
#pragma unroll
        for (int c = 0; c < 8; ++c) { ks[c] = kc[c]; xv[c] = fmaf(0.005f, kc[c], xg[c]); }
        kc = eval_stage(xv, f0yB, f1B, F, D, W, q);
#pragma unroll
        for (int c = 0; c < 8; ++c) { ks[c] = fmaf(2.0f, kc[c], ks[c]); xv[c] = fmaf(0.005f, kc[c], xg[c]); }
        kc = eval_stage(xv, f0yB, f1B, F, D, W, q);
#pragma unroll
        for (int c = 0; c < 8; ++c) { ks[c] = fmaf(2.0f, kc[c], ks[c]); xv[c] = fmaf(0.01f, kc[c], xg[c]); }
        kc = eval_stage(xv, f0yC, f1C, F, D, W, q);

        // ---- store y_t = xG (pre-update) ----
        {
            float s0 = (q == 0) ? xg[0] : (q == 1) ? xg[2] : (q == 2) ? xg[4] : xg[6];
            float s1 = (q == 0) ? xg[1] : (q == 1) ? xg[3] : (q == 2) ? xg[5] : xg[7];
            float2 st = { s0, s1 };
            *(float2*)(ob + t * 8 + 2 * q) = st;
        }

        // ---- state update ----
#pragma unroll
        for (int c = 0; c < 8; ++c) {
            ks[c] += kc[c];
            xg[c] = fmaf(0.0016666667f, ks[c], xg[c]);   // DELTA/6
        }
        // y-ring shift: pure register renaming
        P0 = P1; P1 = P2; P2 = P3; P3 = XC;
        // u shift register
        {
            i4_t Un;
            Un[0] = U[1]; Un[1] = U[2]; Un[2] = U[3]; Un[3] = upair_i;
            U = Un;
        }

        uu = uun;
    }
}

extern "C" void kernel_launch(void* const* d_in, const int* in_sizes, int n_in,
                              void* d_out, int out_size, void* d_ws, size_t ws_size,
                              hipStream_t stream) {
    const float* useq = (const float*)d_in[0];
    const float* xGz0 = (const float*)d_in[1];
    const float* W1   = (const float*)d_in[2];
    const float* b1   = (const float*)d_in[3];
    const float* W2   = (const float*)d_in[4];
    const float* b2   = (const float*)d_in[5];
    const float* W3   = (const float*)d_in[6];
    const float* b3   = (const float*)d_in[7];
    float* out = (float*)d_out;

    // 8192 batch / 16 per group = 512 blocks of 1 wave (all channels)
    cstr_mfma1_kernel<<<dim3(512), dim3(64), 0, stream>>>(
        useq, xGz0, W1, b1, W2, b2, W3, b3, out);
}

// Round 6
// 801.783 us; speedup vs baseline: 1.1219x; 1.0471x over previous
//
#include <hip/hip_runtime.h>

// R10: bit-exact op-diet + chain-overlap pass on R9.
//  (1) fg_eval computed at the HEAD of each RK stage (depends only on x);
//      its ~200-cy serial chain now overlaps the 3 MFMA layers instead of
//      risking a tail position after layer 3.
//  (2) elementwise math in whole-vector f8_t form with
//      __builtin_elementwise_fma -> v_pk_fma_f32/v_pk_mul_f32 emission
//      (2 lanes/issue, per-lane IEEE identical => bit-exact).
//  (3) float2-indexed u/y addressing; y-store issued at step top.
// Carried from R9: all loop state as ext-vector SSA values (no allocas ->
// no LDS/scratch promotion); pi channel permutation (register-local layer
// transitions); permlane16_swap layer-3 gather (W3/b3 duplicated rows);
// sigma-folding tanh(a)=1-2*sigma(2a) with -2, 2*log2(e) folded into
// weights/biases. Numerics bit-identical to R9 (same ops, same order,
// same rounding points) -> absmax must remain exactly 0.015625.

typedef _Float16 h2_t __attribute__((ext_vector_type(2)));
typedef _Float16 h8_t __attribute__((ext_vector_type(8)));
typedef __fp16  pk2_t __attribute__((ext_vector_type(2)));
typedef float f4_t __attribute__((ext_vector_type(4)));
typedef float f8_t __attribute__((ext_vector_type(8)));
typedef int   i4_t __attribute__((ext_vector_type(4)));

union H2I { h2_t h; pk2_t p; int i; float _f; };

#define DEVI __device__ __forceinline__

DEVI float rcp_f(float x) { return __builtin_amdgcn_rcpf(x); }
#if __has_builtin(__builtin_amdgcn_exp2f)
DEVI float exp2_f(float x) { return __builtin_amdgcn_exp2f(x); }
#else
DEVI float exp2_f(float x) { return __expf(x * 0.69314718056f); }
#endif
DEVI int pkrtz_i(float a, float b) { H2I u; u.p = __builtin_amdgcn_cvt_pkrtz(a, b); return u.i; }
DEVI int h2i(h2_t h) { H2I u; u.h = h; return u.i; }
DEVI h2_t i2h(int i) { H2I u; u.i = i; return u.h; }

#if __has_builtin(__builtin_elementwise_fma)
DEVI f8_t fma8(f8_t a, f8_t b, f8_t c) { return __builtin_elementwise_fma(a, b, c); }
#else
DEVI f8_t fma8(f8_t a, f8_t b, f8_t c) {
    f8_t r;
#pragma unroll
    for (int i = 0; i < 8; ++i) r[i] = fmaf(a[i], b[i], c[i]);
    return r;
}
#endif
DEVI f8_t splat8(float v) { f8_t r = { v, v, v, v, v, v, v, v }; return r; }

DEVI f4_t mfma16(h8_t a, h8_t b, f4_t c) {
    return __builtin_amdgcn_mfma_f32_16x16x32_f16(a, b, c, 0, 0, 0);
}

// hidden-channel permutation: physical channel computed at A-tile ct, row rho
DEVI int chan_of(int ct, int rho) {
    int qr = rho >> 2, rr = rho & 3;
    return (ct < 2) ? (8 * qr + 4 * ct + rr)
                    : (32 + 8 * qr + 4 * (ct - 2) + rr);
}

// grey-box CSTR+flash RHS, scaled coords, per-lane (batch = lane&15).
// Head/tail in whole-vector form (v_pk_*), middle scalar (heterogeneous).
DEVI f8_t fg_eval(f8_t x, float F, float D) {
    const f8_t ystd  = { 0.3f, 0.2f, 0.2f, 5.0f, 0.3f, 0.2f, 0.2f, 5.0f };
    const f8_t ymean = { 0.7f, 0.5f, 0.5f, 310.0f, 0.7f, 0.5f, 0.5f, 310.0f };
    f8_t xs = fma8(x, ystd, ymean);

    float Hr  = xs[0], CAr = xs[1], CBr = xs[2], Tr = xs[3];
    float Hb  = xs[4], CAb = xs[5], CBb = xs[6], Tb = xs[7];

    float aA = 3.5f * CAb, aB = 1.1f * CBb;
    float rden = rcp_f(aA + aB);
    float CAd = aA * rden, CBd = aB * rden;
    float Fr = __builtin_amdgcn_sqrtf(Hr);
    float Fb = __builtin_amdgcn_sqrtf(Hb);
    float rTr = rcp_f(Tr);
    float k1v = 20000.0f * __expf(-3000.0f * rTr);
    float r1 = k1v * CAr;
    float rHr = rcp_f(Hr), rHb = rcp_f(Hb);

    f8_t d;
    d[0] = F + D - Fr;
    d[1] = (F * (1.0f - CAr) + D * (CAd - CAr)) * rHr - r1;
    d[2] = (D * (CBd - CBr) - F * CBr) * rHr + r1;
    d[3] = (F * (320.0f - Tr) + D * (310.0f - Tr)) * rHr
         - (40.0f / 3.0f) * rHr + (2.0f / 3.0f) * r1;
    d[4] = Fr - Fb - D;
    d[5] = (Fr * (CAr - CAb) + D * (CAb - CAd)) * rHb;
    d[6] = (Fr * (CBr - CBb) + D * (CBb - CBd)) * rHb;
    d[7] = Fr * (Tr - Tb) * rHb + (40.0f / 3.0f) * rHb;

    const f8_t sc = { 10.0f / 3.0f, 5.0f, 5.0f, 0.2f,
                      10.0f / 3.0f, 5.0f, 5.0f, 0.2f };
    return d * sc;
}

struct Weights {
    h8_t a1[4][2], a2[4][2], a3[2];
    f4_t b1f[4], b2f[4], b3f;
};

DEVI int sigpair(float a, float b) {
    float s0 = rcp_f(1.0f + exp2_f(a));
    float s1 = rcp_f(1.0f + exp2_f(b));
    return pkrtz_i(s0, s1);
}

// sigma transition for two C-tiles -> one B-frag (register-local, SSA)
DEVI h8_t sig4(f4_t a0, f4_t a1) {
    i4_t g;
    g[0] = sigpair(a0[0], a0[1]);
    g[1] = sigpair(a0[2], a0[3]);
    g[2] = sigpair(a1[0], a1[1]);
    g[3] = sigpair(a1[2], a1[3]);
    return __builtin_bit_cast(h8_t, g);
}

// packed-f16 midpoint of 4 pairs: (a+b)*0.5h, same rounding as before
DEVI i4_t avg4(i4_t A, i4_t B) {
    const h2_t half2c = { (_Float16)0.5f, (_Float16)0.5f };
    i4_t r;
#pragma unroll
    for (int i = 0; i < 4; ++i)
        r[i] = h2i((i2h(A[i]) + i2h(B[i])) * half2c);
    return r;
}

// f0 y-part select: quad q picks its 4 pair-words of the variant
DEVI i4_t sel_f0y(i4_t V0, i4_t V1, i4_t V2, int q) {
    i4_t r;
#pragma unroll
    for (int i = 0; i < 4; ++i) {
        int t = (q == 2) ? V1[i] : V2[i];
        r[i] = (q == 1) ? V0[i] : t;
    }
    return r;
}
// f1 select: q0 lanes get variant pairs 12..15, others the common u-part
DEVI i4_t sel_f1(i4_t V3, i4_t f1c, int q) {
    i4_t r;
#pragma unroll
    for (int i = 0; i < 4; ++i)
        r[i] = (q == 0) ? V3[i] : f1c[i];
    return r;
}

// one RK slope: k = fg(x,u) + fnn([x, zvariant, u]); fg issued FIRST so its
// serial chain overlaps the MFMA layers; y/u frag words are precomputed.
DEVI f8_t eval_stage(f8_t x, i4_t f0y, i4_t f1w,
                     float F, float D, const Weights& W, int q) {
    f8_t kfg = fg_eval(x, F, D);            // independent of the NN below

    i4_t f0w;
#pragma unroll
    for (int i = 0; i < 4; ++i) {
        int pxi = pkrtz_i(x[2 * i], x[2 * i + 1]);
        f0w[i] = (q == 0) ? pxi : f0y[i];
    }
    h8_t f0 = __builtin_bit_cast(h8_t, f0w);
    h8_t f1 = __builtin_bit_cast(h8_t, f1w);

    // ---- layer 1 (4 M-tiles, pi-permuted channels) ----
    f4_t a0 = mfma16(W.a1[0][0], f0, W.b1f[0]); a0 = mfma16(W.a1[0][1], f1, a0);
    f4_t a1 = mfma16(W.a1[1][0], f0, W.b1f[1]); a1 = mfma16(W.a1[1][1], f1, a1);
    f4_t a2 = mfma16(W.a1[2][0], f0, W.b1f[2]); a2 = mfma16(W.a1[2][1], f1, a2);
    f4_t a3 = mfma16(W.a1[3][0], f0, W.b1f[3]); a3 = mfma16(W.a1[3][1], f1, a3);
    h8_t g0 = sig4(a0, a1);
    h8_t g1 = sig4(a2, a3);

    // ---- layer 2 ----
    a0 = mfma16(W.a2[0][0], g0, W.b2f[0]); a0 = mfma16(W.a2[0][1], g1, a0);
    a1 = mfma16(W.a2[1][0], g0, W.b2f[1]); a1 = mfma16(W.a2[1][1], g1, a1);
    a2 = mfma16(W.a2[2][0], g0, W.b2f[2]); a2 = mfma16(W.a2[2][1], g1, a2);
    a3 = mfma16(W.a2[3][0], g0, W.b2f[3]); a3 = mfma16(W.a2[3][1], g1, a3);
    g0 = sig4(a0, a1);
    g1 = sig4(a2, a3);

    // ---- layer 3 (full K; rows duplicated ch=row&7) ----
    f4_t acc3 = mfma16(W.a3[0], g0, W.b3f);
    acc3 = mfma16(W.a3[1], g1, acc3);

    // gather: acc3 reg r holds [ch r, ch 4+r, ch r, ch 4+r] across 16-lane
    // groups; self permlane16_swap -> ch r and ch 4+r on every lane.
    f8_t nn;
#pragma unroll
    for (int r = 0; r < 4; ++r) {
        int e = __float_as_int(acc3[r]);
        int o = e;
        asm("v_permlane16_swap_b32 %0, %1" : "+v"(e), "+v"(o));
        nn[r]     = __int_as_float(e);
        nn[4 + r] = __int_as_float(o);
    }

    return kfg + nn;
}

__global__ __launch_bounds__(64, 1)
void cstr_mfma1_kernel(const float* __restrict__ useq, const float* __restrict__ xGz0,
                       const float* __restrict__ W1, const float* __restrict__ b1,
                       const float* __restrict__ W2, const float* __restrict__ b2,
                       const float* __restrict__ W3, const float* __restrict__ b3,
                       float* __restrict__ out)
{
    const int lane = threadIdx.x & 63;
    const int m16 = lane & 15, q = lane >> 4;
    const int b0 = blockIdx.x * 16;

    const float S1 = 2.0f * 1.4426950408889634f;   // 2*log2(e)

    // ---- preload weights (sigma-folded, pi-permuted output columns) ----
    Weights W;
#pragma unroll
    for (int ct = 0; ct < 4; ++ct) {
        const int n = chan_of(ct, m16);            // A-frag row m16 -> channel
#pragma unroll
        for (int kh = 0; kh < 2; ++kh) {
            i4_t w1f, w2f;
#pragma unroll
            for (int jj = 0; jj < 4; ++jj) {
                int k0 = 32 * kh + 8 * q + 2 * jj;
                int k1 = k0 + 1;
                float v1a = (k0 < 50) ? S1 * W1[k0 * 64 + n] : 0.0f;
                float v1b = (k1 < 50) ? S1 * W1[k1 * 64 + n] : 0.0f;
                float v2a = -2.0f * S1 * W2[k0 * 64 + n];
                float v2b = -2.0f * S1 * W2[k1 * 64 + n];
                w1f[jj] = pkrtz_i(v1a, v1b);
                w2f[jj] = pkrtz_i(v2a, v2b);
            }
            W.a1[ct][kh] = __builtin_bit_cast(h8_t, w1f);
            W.a2[ct][kh] = __builtin_bit_cast(h8_t, w2f);
        }
        f4_t bb1, bb2;
#pragma unroll
        for (int r = 0; r < 4; ++r) {
            int ch = chan_of(ct, 4 * q + r);       // C slot (ct,q,r) -> channel
            bb1[r] = S1 * b1[ch];
            float cs = 0.0f;
            for (int j = 0; j < 64; ++j) cs += W2[j * 64 + ch];
            bb2[r] = S1 * (b2[ch] + cs);
        }
        W.b1f[ct] = bb1;
        W.b2f[ct] = bb2;
    }
    // layer 3: duplicate channels into rows 8-15 (ch = row&7) for the
    // permlane gather; duplicated rows are identical independent dots.
#pragma unroll
    for (int kh = 0; kh < 2; ++kh) {
        i4_t w3f;
#pragma unroll
        for (int jj = 0; jj < 4; ++jj) {
            int k0 = 32 * kh + 8 * q + 2 * jj;
            float va = -2.0f * W3[k0 * 8 + (m16 & 7)];
            float vb = -2.0f * W3[(k0 + 1) * 8 + (m16 & 7)];
            w3f[jj] = pkrtz_i(va, vb);
        }
        W.a3[kh] = __builtin_bit_cast(h8_t, w3f);
    }
    {
        f4_t bb3;
#pragma unroll
        for (int r = 0; r < 4; ++r) {
            int c = (4 * q + r) & 7;
            float cs = 0.0f;
            for (int j = 0; j < 64; ++j) cs += W3[j * 8 + c];
            bb3[r] = b3[c] + cs;
        }
        W.b3f = bb3;
    }

    // ---- per-batch state (batch = lane&15; replicated across quads) ----
    const float* xz = xGz0 + (size_t)(b0 + m16) * 48;
    f8_t xg;
#pragma unroll
    for (int c = 0; c < 8; ++c) xg[c] = xz[c];
    // y-ring as packed h2 pair-words: P0=pairs0-3, P1=4-7, P2=8-11, P3=12-15
    i4_t P0, P1, P2, P3, U;
#pragma unroll
    for (int i = 0; i < 4; ++i) {
        P0[i] = pkrtz_i(xz[ 8 + 2 * i], xz[ 9 + 2 * i]);
        P1[i] = pkrtz_i(xz[16 + 2 * i], xz[17 + 2 * i]);
        P2[i] = pkrtz_i(xz[24 + 2 * i], xz[25 + 2 * i]);
        P3[i] = pkrtz_i(xz[32 + 2 * i], xz[33 + 2 * i]);
        U[i]  = pkrtz_i(xz[40 + 2 * i], xz[41 + 2 * i]);
    }

    const float2* ur = (const float2*)(useq + (size_t)(b0 + m16) * 512);
    float2* ow = (float2*)(out + (size_t)(b0 + m16) * 2048) + q;

    float2 uu = ur[0];                      // u for t=0

    const f8_t c005  = splat8(0.005f);
    const f8_t c01   = splat8(0.01f);
    const f8_t c2    = splat8(2.0f);
    const f8_t cD6   = splat8(0.0016666667f);   // DELTA/6

#pragma unroll 1
    for (int t = 0; t < 256; ++t) {
        // prefetch next step's u (wraps harmlessly at t=255)
        const float2 uun = ur[(t + 1) & 255];

        // ---- store y_t = xG early (pre-update; fire-and-forget) ----
        {
            float s0 = (q == 0) ? xg[0] : (q == 1) ? xg[2] : (q == 2) ? xg[4] : xg[6];
            float s1 = (q == 0) ? xg[1] : (q == 1) ? xg[3] : (q == 2) ? xg[5] : xg[7];
            float2 st = { s0, s1 };
            ow[t * 4] = st;
        }

        const float u0 = uu.x, u1 = uu.y;
        const float F = fmaf(u0, 0.1f, 1.0f);
        const float D = fmaf(u1, 0.05f, 0.5f);
        const int upair_i = pkrtz_i(u0, u1);

        // xG pairs (pc[16..19])
        i4_t XC;
#pragma unroll
        for (int i = 0; i < 4; ++i) XC[i] = pkrtz_i(xg[2 * i], xg[2 * i + 1]);

        // variant B (midpoint) pair-words
        i4_t B0 = avg4(P0, P1), B1 = avg4(P1, P2),
             B2 = avg4(P2, P3), B3 = avg4(P3, XC);

        // common u-part of f1
        i4_t f1c;
#pragma unroll
        for (int i = 0; i < 4; ++i) {
            int t0 = (i == 0) ? ((q == 2) ? upair_i : 0) : 0;
            f1c[i] = (q == 1) ? U[i] : t0;
        }

        // stage-invariant frag words (all SSA)
        i4_t f0yA = sel_f0y(P0, P1, P2, q), f1A = sel_f1(P3, f1c, q);
        i4_t f0yB = sel_f0y(B0, B1, B2, q), f1B = sel_f1(B3, f1c, q);
        i4_t f0yC = sel_f0y(P1, P2, P3, q), f1C = sel_f1(XC, f1c, q);

        // ---- RK4 (all register-local; no LDS, no DS, no barriers) ----
        f8_t kc, ks, xv;
        kc = eval_stage(xg, f0yA, f1A, F, D, W, q);
        ks = kc;
        xv = fma8(c005, kc, xg);
        kc = eval_stage(xv, f0yB, f1B, F, D, W, q);
        ks = fma8(c2, kc, ks);
        xv = fma8(c005, kc, xg);
        kc = eval_stage(xv, f0yB, f1B, F, D, W, q);
        ks = fma8(c2, kc, ks);
        xv = fma8(c01, kc, xg);
        kc = eval_stage(xv, f0yC, f1C, F, D, W, q);

        // ---- state update ----
        ks = ks + kc;
        xg = fma8(cD6, ks, xg);

        // y-ring shift: pure register renaming
        P0 = P1; P1 = P2; P2 = P3; P3 = XC;
        // u shift register
        {
            i4_t Un;
            Un[0] = U[1]; Un[1] = U[2]; Un[2] = U[3]; Un[3] = upair_i;
            U = Un;
        }

        uu = uun;
    }
}

extern "C" void kernel_launch(void* const* d_in, const int* in_sizes, int n_in,
                              void* d_out, int out_size, void* d_ws, size_t ws_size,
                              hipStream_t stream) {
    const float* useq = (const float*)d_in[0];
    const float* xGz0 = (const float*)d_in[1];
    const float* W1   = (const float*)d_in[2];
    const float* b1   = (const float*)d_in[3];
    const float* W2   = (const float*)d_in[4];
    const float* b2   = (const float*)d_in[5];
    const float* W3   = (const float*)d_in[6];
    const float* b3   = (const float*)d_in[7];
    float* out = (float*)d_out;

    // 8192 batch / 16 per group = 512 blocks of 1 wave (all channels)
    cstr_mfma1_kernel<<<dim3(512), dim3(64), 0, stream>>>(
        useq, xGz0, W1, b1, W2, b2, W3, b3, out);
}